// Round 2
// baseline (526.185 us; speedup 1.0000x reference)
//
#include <hip/hip_runtime.h>
#include <hip/hip_bf16.h>
#include <math.h>

// ---------------------------------------------------------------------------
// ModelFC_49134425866355 on MI355X (gfx950)
//
// Pipeline:
//   prep:   E fp32 -> bf16 ; W1 -> W1t bf16 [1536][768] ; W2 -> W2t bf16 [128][1536] (pad rows 100..127 = 0)
//   gemm1:  act = bf16( gelu_exact( E@W1 + b1 ) )        [32768][1536]   (MFMA 16x16x32 bf16)
//   ln:     act = LN(act)*g + b  (in place, per row, eps=1e-12)
//   gemm2:  logits fp32 = act@W2 + b2                    [32768][100]
//   own:    exact fp32 recompute of the 512 "own" rows -> own_logits [512][100]
//           (own row of entity e=8a+j is global row a*512 + 8a + j = 520a + j)
//   final:  VG_scores / VG_index / sel from own_logits (fp32-exact argmax!)
//   scores: out[t*8+k] = logits[t, sel]  (t = l*512 + m*8 + j)
// ---------------------------------------------------------------------------

typedef __bf16 bf16_t;
typedef __bf16  bf16x8  __attribute__((ext_vector_type(8)));
typedef float   floatx4 __attribute__((ext_vector_type(4)));

__device__ __forceinline__ float gelu_exact(float x) {
    return 0.5f * x * (1.0f + erff(x * 0.7071067811865475f));
}

// async global->LDS, 16B per lane; lds base must be wave-uniform (HW adds lane*16)
__device__ __forceinline__ void gl_lds16(const bf16_t* g, bf16_t* l) {
    __builtin_amdgcn_global_load_lds(
        (const __attribute__((address_space(1))) void*)g,
        (__attribute__((address_space(3))) void*)l, 16, 0, 0);
}

// ---------------------------------------------------------------------------
// prep kernels
// ---------------------------------------------------------------------------
__global__ __launch_bounds__(256) void cvt_e(const float4* __restrict__ in,
                                             bf16_t* __restrict__ outp, int n4) {
    int t = blockIdx.x * 256 + threadIdx.x;
    if (t >= n4) return;
    float4 v = in[t];
    union { bf16_t h[4]; uint2 u; } u;
    u.h[0] = (bf16_t)v.x; u.h[1] = (bf16_t)v.y;
    u.h[2] = (bf16_t)v.z; u.h[3] = (bf16_t)v.w;
    *(uint2*)(outp + (size_t)t * 4) = u.u;
}

// W1 [768][1536] fp32 -> W1t [1536][768] bf16 (writes coalesced)
__global__ __launch_bounds__(256) void tr_w1(const float* __restrict__ W1,
                                             bf16_t* __restrict__ W1t) {
    int t = blockIdx.x * 256 + threadIdx.x;   // 1536*768 threads exactly
    int k = t % 768, n = t / 768;
    W1t[t] = (bf16_t)W1[(size_t)k * 1536 + n];
}

// W2 [1536][100] fp32 -> W2t [128][1536] bf16, pad rows n>=100 with zeros
__global__ __launch_bounds__(256) void tr_w2(const float* __restrict__ W2,
                                             bf16_t* __restrict__ W2t) {
    int t = blockIdx.x * 256 + threadIdx.x;   // 128*1536 threads exactly
    int k = t % 1536, n = t / 1536;
    W2t[t] = (n < 100) ? (bf16_t)W2[(size_t)k * 100 + n] : (bf16_t)0.0f;
}

// ---------------------------------------------------------------------------
// m97-style bf16 MFMA GEMM, A [M][K] bf16, Bt [N][K] bf16 (both K-contiguous).
// 128x128 block tile, BK=64, 4 waves each computing 64x64 via 4x4 MFMA tiles.
// XOR swizzle on 16B k-chunks (chunk ^= row&7) to break LDS bank aliasing;
// swizzle applied on the GLOBAL source so global_load_lds stays lane-contiguous.
// MODE 0: C = bf16(gelu(acc + bias[n])), stride N.  MODE 1: fp32 out, n<nout.
// ---------------------------------------------------------------------------
template<int MODE>
__global__ __launch_bounds__(256) void mfma_gemm_bt(
        const bf16_t* __restrict__ A, const bf16_t* __restrict__ Bt,
        const float* __restrict__ bias, void* __restrict__ Cout,
        int M, int N, int K, int nout) {
    __shared__ alignas(16) bf16_t sA[128 * 64];   // [row m][64 k], 16 KB
    __shared__ alignas(16) bf16_t sB[128 * 64];   // [row n][64 k], 16 KB

    const int tid  = threadIdx.x;
    const int lane = tid & 63;
    const int wave = tid >> 6;
    const int wr = wave >> 1, wc = wave & 1;     // 2x2 waves over 128x128
    const int m0 = blockIdx.y * 128;
    const int n0 = blockIdx.x * 128;
    const int q  = lane >> 4;                    // quad 0..3
    const int l15 = lane & 15;

    floatx4 acc[4][4] = {};

    const int nK = K >> 6;
    for (int kt = 0; kt < nK; ++kt) {
        const int k0 = kt * 64;
        __syncthreads();   // previous compute done before LDS overwrite
        #pragma unroll
        for (int c = 0; c < 4; ++c) {
            const int s    = c * 256 + tid;
            const int row  = s >> 3;             // 8 slots of 16B per 64-k row
            const int col  = s & 7;
            const int gcol = col ^ (row & 7);    // source-side swizzle
            gl_lds16(A  + (size_t)(m0 + row) * K + k0 + gcol * 8,
                     sA + (c * 256 + wave * 64) * 8);
            gl_lds16(Bt + (size_t)(n0 + row) * K + k0 + gcol * 8,
                     sB + (c * 256 + wave * 64) * 8);
        }
        __syncthreads();   // drains vmcnt(0) for global_load_lds, then barrier

        #pragma unroll
        for (int ks = 0; ks < 2; ++ks) {
            bf16x8 af[4], bfr[4];
            const int chunk = ((ks * 4 + q) ^ (lane & 7));  // row&7 == lane&7 here
            #pragma unroll
            for (int t4 = 0; t4 < 4; ++t4) {
                const int rA = wr * 64 + t4 * 16 + l15;
                const int rB = wc * 64 + t4 * 16 + l15;
                af[t4]  = *(const bf16x8*)(sA + rA * 64 + chunk * 8);
                bfr[t4] = *(const bf16x8*)(sB + rB * 64 + chunk * 8);
            }
            #pragma unroll
            for (int mt = 0; mt < 4; ++mt)
                #pragma unroll
                for (int nt = 0; nt < 4; ++nt)
                    acc[mt][nt] = __builtin_amdgcn_mfma_f32_16x16x32_bf16(
                        af[mt], bfr[nt], acc[mt][nt], 0, 0, 0);
        }
    }

    // epilogue: C/D layout col = lane&15, row = (lane>>4)*4 + r  [m89 verified]
    #pragma unroll
    for (int mt = 0; mt < 4; ++mt) {
        #pragma unroll
        for (int nt = 0; nt < 4; ++nt) {
            const int n = n0 + wc * 64 + nt * 16 + l15;
            const float bv = (n < nout) ? bias[n] : 0.0f;
            #pragma unroll
            for (int r = 0; r < 4; ++r) {
                const int m = m0 + wr * 64 + mt * 16 + q * 4 + r;
                const float v = acc[mt][nt][r] + bv;
                if (MODE == 0) {
                    ((bf16_t*)Cout)[(size_t)m * N + n] = (bf16_t)gelu_exact(v);
                } else {
                    if (n < nout) ((float*)Cout)[(size_t)m * nout + n] = v;
                }
            }
        }
    }
}

// ---------------------------------------------------------------------------
// per-row LayerNorm in place over act bf16 [32768][1536], eps = 1e-12
// ---------------------------------------------------------------------------
__global__ __launch_bounds__(256) void ln_rows(bf16_t* __restrict__ act,
                                               const float* __restrict__ lng,
                                               const float* __restrict__ lnb) {
    const int row = blockIdx.x, tid = threadIdx.x;
    bf16_t* p = act + (size_t)row * 1536;
    float x[6];
    #pragma unroll
    for (int i = 0; i < 6; ++i) x[i] = (float)p[tid + i * 256];

    __shared__ float red[256];
    float s = 0.f;
    #pragma unroll
    for (int i = 0; i < 6; ++i) s += x[i];
    red[tid] = s; __syncthreads();
    for (int off = 128; off > 0; off >>= 1) {
        if (tid < off) red[tid] += red[tid + off];
        __syncthreads();
    }
    const float mu = red[0] * (1.0f / 1536.0f);
    __syncthreads();

    float s2 = 0.f;
    #pragma unroll
    for (int i = 0; i < 6; ++i) { float d = x[i] - mu; s2 += d * d; }
    red[tid] = s2; __syncthreads();
    for (int off = 128; off > 0; off >>= 1) {
        if (tid < off) red[tid] += red[tid + off];
        __syncthreads();
    }
    const float rstd = rsqrtf(red[0] * (1.0f / 1536.0f) + 1e-12f);

    #pragma unroll
    for (int i = 0; i < 6; ++i) {
        const int c = tid + i * 256;
        p[c] = (bf16_t)((x[i] - mu) * rstd * lng[c] + lnb[c]);
    }
}

// ---------------------------------------------------------------------------
// exact fp32 recompute of the 512 "own" rows. Block a (0..63) handles
// entities e = 8a..8a+7, whose own rows are the CONTIGUOUS global rows
// 520a .. 520a+7  (row = a*512 + 8a + j).
// Feeds argmax / softmax-max / sel -> must NOT go through bf16.
// ---------------------------------------------------------------------------
__global__ __launch_bounds__(512) void own_rows(
        const float* __restrict__ E,  const float* __restrict__ W1,
        const float* __restrict__ b1, const float* __restrict__ lng,
        const float* __restrict__ lnb, const float* __restrict__ W2,
        const float* __restrict__ b2, float* __restrict__ own) {
    const int a = blockIdx.x;         // 0..63
    const int tid = threadIdx.x;      // 0..511
    __shared__ float sE[8][768];      // 24 KB
    __shared__ float sh[8][1536];     // 48 KB
    __shared__ float red[512];        // 2 KB

    for (int i = tid; i < 8 * 768; i += 512)
        sE[i / 768][i % 768] = E[(size_t)(520 * a) * 768 + i];  // rows 520a..520a+7
    __syncthreads();

    // h = E_rows @ W1 : thread owns cols {tid, tid+512, tid+1024} x 8 rows
    float acc[3][8] = {};
    for (int k = 0; k < 768; ++k) {
        float e[8];
        #pragma unroll
        for (int j = 0; j < 8; ++j) e[j] = sE[j][k];   // LDS broadcast
        #pragma unroll
        for (int i = 0; i < 3; ++i) {
            const float w = W1[(size_t)k * 1536 + tid + i * 512];
            #pragma unroll
            for (int j = 0; j < 8; ++j) acc[i][j] += w * e[j];
        }
    }
    #pragma unroll
    for (int i = 0; i < 3; ++i) {
        const int c = tid + i * 512;
        const float bb = b1[c];
        #pragma unroll
        for (int j = 0; j < 8; ++j) sh[j][c] = gelu_exact(acc[i][j] + bb);
    }
    __syncthreads();

    // LayerNorm each of the 8 rows (two-pass, fp32)
    for (int j = 0; j < 8; ++j) {
        float s = sh[j][tid] + sh[j][tid + 512] + sh[j][tid + 1024];
        red[tid] = s; __syncthreads();
        for (int off = 256; off > 0; off >>= 1) {
            if (tid < off) red[tid] += red[tid + off];
            __syncthreads();
        }
        const float mu = red[0] * (1.0f / 1536.0f);
        __syncthreads();
        float d0 = sh[j][tid] - mu, d1 = sh[j][tid + 512] - mu, d2 = sh[j][tid + 1024] - mu;
        red[tid] = d0 * d0 + d1 * d1 + d2 * d2; __syncthreads();
        for (int off = 256; off > 0; off >>= 1) {
            if (tid < off) red[tid] += red[tid + off];
            __syncthreads();
        }
        const float rstd = rsqrtf(red[0] * (1.0f / 1536.0f) + 1e-12f);
        __syncthreads();
        #pragma unroll
        for (int i = 0; i < 3; ++i) {
            const int c = tid + i * 512;
            sh[j][c] = (sh[j][c] - mu) * rstd * lng[c] + lnb[c];
        }
        __syncthreads();
    }

    // own_logits = sh @ W2 + b2 : thread (d = tid&127, jg = tid>>7) does 2 rows
    const int d = tid & 127, jg = tid >> 7;
    if (d < 100) {
        float a0 = b2[d], a1 = b2[d];
        for (int k = 0; k < 1536; ++k) {
            const float w = W2[(size_t)k * 100 + d];
            a0 += sh[2 * jg][k] * w;
            a1 += sh[2 * jg + 1][k] * w;
        }
        own[(size_t)(a * 8 + 2 * jg) * 100 + d]     = a0;
        own[(size_t)(a * 8 + 2 * jg + 1) * 100 + d] = a1;
    }
}

// ---------------------------------------------------------------------------
// VG_scores (max softmax = 1/sum exp(x-max)), VG_index (first-max argmax), sel
// ---------------------------------------------------------------------------
__global__ __launch_bounds__(256) void finalize(const float* __restrict__ own,
                                                float* __restrict__ out,
                                                int* __restrict__ sel) {
    const int e = blockIdx.x * 256 + threadIdx.x;
    if (e >= 512) return;
    const float* r = own + (size_t)e * 100;
    float best = r[0]; int bi = 0;
    for (int i = 1; i < 100; ++i) {
        const float v = r[i];
        if (v > best) { best = v; bi = i; }       // strict > keeps first max
    }
    float s = 0.f;
    for (int i = 0; i < 100; ++i) s += expf(r[i] - best);
    out[262144 + e] = 1.0f / s;                   // VG_scores
    out[262656 + e] = (float)bi;                  // VG_scores_index (as fp32)
    if (e == 511) *sel = bi;
}

// scores[0,l,m,j,k] = logits[l*512+m*8+j, sel] ; out flat = t*8+k, t=l*512+m*8+j
__global__ __launch_bounds__(256) void scores_out(const float* __restrict__ logits,
                                                  const int* __restrict__ selp,
                                                  float* __restrict__ out) {
    const int t = blockIdx.x * 256 + threadIdx.x; // 32768 threads exactly
    const int sel = *selp;
    const float v = logits[(size_t)t * 100 + sel];
    const float4 f = make_float4(v, v, v, v);
    float4* o = (float4*)(out + (size_t)t * 8);
    o[0] = f; o[1] = f;
}

// ---------------------------------------------------------------------------
extern "C" void kernel_launch(void* const* d_in, const int* in_sizes, int n_in,
                              void* d_out, int out_size, void* d_ws, size_t ws_size,
                              hipStream_t stream) {
    const float* E   = (const float*)d_in[0];
    const float* W1  = (const float*)d_in[1];
    const float* b1  = (const float*)d_in[2];
    const float* lng = (const float*)d_in[3];
    const float* lnb = (const float*)d_in[4];
    const float* W2  = (const float*)d_in[5];
    const float* b2  = (const float*)d_in[6];
    float* out = (float*)d_out;

    char* w = (char*)d_ws;
    auto carve = [&](size_t bytes) {
        void* p = (void*)w;
        w += (bytes + 255) & ~(size_t)255;
        return p;
    };
    bf16_t* Ebf    = (bf16_t*)carve((size_t)25165824 * 2);   // 50.3 MB
    bf16_t* W1t    = (bf16_t*)carve((size_t)1536 * 768 * 2); //  2.4 MB
    bf16_t* W2t    = (bf16_t*)carve((size_t)128 * 1536 * 2); //  0.4 MB
    bf16_t* act    = (bf16_t*)carve((size_t)32768 * 1536 * 2); // 100.7 MB
    float*  logits = (float*)carve((size_t)32768 * 100 * 4); // 13.1 MB
    float*  own    = (float*)carve((size_t)512 * 100 * 4);
    int*    sel    = (int*)carve(256);

    cvt_e<<<24576, 256, 0, stream>>>((const float4*)E, Ebf, 6291456);
    tr_w1<<<4608, 256, 0, stream>>>(W1, W1t);
    tr_w2<<<768, 256, 0, stream>>>(W2, W2t);

    // GEMM1: [32768,768] @ [768,1536] -> act (gelu, bf16)
    mfma_gemm_bt<0><<<dim3(12, 256), 256, 0, stream>>>(Ebf, W1t, b1, act,
                                                       32768, 1536, 768, 1536);
    ln_rows<<<32768, 256, 0, stream>>>(act, lng, lnb);
    // GEMM2: [32768,1536] @ [1536,100(pad 128)] -> logits fp32
    mfma_gemm_bt<1><<<dim3(1, 256), 256, 0, stream>>>(act, W2t, b2, logits,
                                                      32768, 128, 1536, 100);

    own_rows<<<64, 512, 0, stream>>>(E, W1, b1, lng, lnb, W2, b2, own);
    finalize<<<2, 256, 0, stream>>>(own, out, sel);
    scores_out<<<128, 256, 0, stream>>>(logits, sel, out);
}